// Round 4
// baseline (346.971 us; speedup 1.0000x reference)
//
#include <hip/hip_runtime.h>
#include <hip/hip_bf16.h>
#include <math.h>

// ALALLaDA router blend, factored + row-compacted form:
//   scan: unm_idx = positions with mask==0 (count Nu), order-preserving;
//         msk_idx = masked positions with >=1 valid neighbor (count Nm);
//         ru[t] = exclusive prefix count of unmasked positions.
//   Act_c[i, kf] = gelu(h[unm_idx[i],:]·W1 + b1)          (GEMM1, M=Nu)
//   G_c[i, kf]   = w[a]*sum_{j in [ru[lo],ru[hi+1])} Act_c[j]  (a=msk_idx[i])
//   num_c[i,:]   = G_c[i,:]·W2s                           (GEMM2, M=Nm)
//   out = h + 0.08*LN((num_c+cnt*w·b2)/cnt) at active masked positions.
// GEMM: 128x128 tile, BK=32, 5-buffer depth-4 prefetch, counted vmcnt(12)
// (T3/T4), one s_barrier per K-step, XCD-aware bijective swizzle (T1,
// bn-major chunks: per-XCD B-panel working set 2-4MB fits XCD L2).
// Shapes fixed: B=2, S=2048, D=2048, K=8, Fh=512, KF=4096, NT=4096.

#define ALPHA 0.08f
#define EPS 1e-5f

typedef __attribute__((ext_vector_type(8))) __bf16 bf16x8;
typedef __attribute__((ext_vector_type(8))) short short8;
typedef __attribute__((ext_vector_type(4))) float f32x4;

__device__ __forceinline__ unsigned short f2bf(float f) {
  unsigned u = __float_as_uint(f);
  u += 0x7fffu + ((u >> 16) & 1u);
  return (unsigned short)(u >> 16);
}
__device__ __forceinline__ float bf2f(unsigned short b) {
  return __uint_as_float(((unsigned)b) << 16);
}

#define GLD16(gptr, lptr)                                                     \
  __builtin_amdgcn_global_load_lds(                                           \
      (const __attribute__((address_space(1))) void*)(gptr),                  \
      (__attribute__((address_space(3))) void*)(lptr), 16, 0, 0)

__device__ __forceinline__ int wave_incl_scan(int v, int lane) {
#pragma unroll
  for (int off = 1; off < 64; off <<= 1) {
    int t = __shfl_up(v, off);
    if (lane >= off) v += t;
  }
  return v;
}

// ---------------- compaction scan (single block) ----------------
__global__ __launch_bounds__(1024) void scan_kernel(
    const int* __restrict__ mask, const int* __restrict__ rptr,
    int* __restrict__ ru, int* __restrict__ unm_idx,
    int* __restrict__ msk_idx, int* __restrict__ pos2row,
    int* __restrict__ counts) {
  __shared__ int sru[4097];
  __shared__ int wsum[16];
  __shared__ int wsum2[17];
  const int tid = threadIdx.x;
  const int lane = tid & 63, wv = tid >> 6;
  const int t0 = tid * 4;
  const int4 m4 = *(const int4*)(mask + t0);
  int f[4];
  f[0] = (m4.x == 0); f[1] = (m4.y == 0); f[2] = (m4.z == 0); f[3] = (m4.w == 0);
  const int tsum = f[0] + f[1] + f[2] + f[3];
  const int isc = wave_incl_scan(tsum, lane);
  if (lane == 63) wsum[wv] = isc;
  __syncthreads();
  if (tid == 0) {
    int acc = 0;
#pragma unroll
    for (int i = 0; i < 16; ++i) { int v = wsum[i]; wsum[i] = acc; acc += v; }
    sru[4096] = acc;
    counts[0] = acc;
    ru[4096] = acc;
  }
  __syncthreads();
  int ex = wsum[wv] + isc - tsum;
#pragma unroll
  for (int j = 0; j < 4; ++j) {
    sru[t0 + j] = ex;
    ru[t0 + j] = ex;
    if (f[j]) unm_idx[ex] = t0 + j;
    ex += f[j];
  }
  __syncthreads();
  // pass 2: masked positions with >=1 valid neighbor
  const int r = rptr[0];
  int mval[4] = {m4.x, m4.y, m4.z, m4.w};
  int g[4];
#pragma unroll
  for (int j = 0; j < 4; ++j) {
    const int t = t0 + j;
    const int s = t & 2047, tb = t & ~2047;
    const int lo = max(s - r, 0), hi = min(s + r, 2047);
    const int cnt = sru[tb + hi + 1] - sru[tb + lo];
    g[j] = (mval[j] != 0 && cnt > 0) ? 1 : 0;
  }
  const int tsum2 = g[0] + g[1] + g[2] + g[3];
  const int isc2 = wave_incl_scan(tsum2, lane);
  if (lane == 63) wsum2[wv] = isc2;
  __syncthreads();
  if (tid == 0) {
    int acc = 0;
#pragma unroll
    for (int i = 0; i < 16; ++i) { int v = wsum2[i]; wsum2[i] = acc; acc += v; }
    counts[1] = acc;
  }
  __syncthreads();
  int ex2 = wsum2[wv] + isc2 - tsum2;
#pragma unroll
  for (int j = 0; j < 4; ++j) {
    const int t = t0 + j;
    pos2row[t] = g[j] ? ex2 : -1;
    if (g[j]) msk_idx[ex2] = t;
    ex2 += g[j];
  }
}

// ---------------- fused: router softmax + bf16 pack of unmasked h rows ----
__global__ void packrouter_kernel(const float* __restrict__ h,
                                  const int* __restrict__ mask,
                                  const int* __restrict__ ru,
                                  const float* __restrict__ Wr,
                                  const float* __restrict__ br,
                                  float* __restrict__ w,
                                  unsigned short* __restrict__ hbc) {
  const int a = blockIdx.x;
  const int tid = threadIdx.x;
  const int lane = tid & 63, wid = tid >> 6;
  const size_t base = (size_t)a * 2048;
  const int d0 = tid * 8;
  float hv[8];
  *(float4*)(hv) = *(const float4*)(h + base + d0);
  *(float4*)(hv + 4) = *(const float4*)(h + base + d0 + 4);
  float acc[8];
#pragma unroll
  for (int k = 0; k < 8; ++k) {
    float wvv[8];
    *(float4*)(wvv) = *(const float4*)(Wr + (size_t)k * 2048 + d0);
    *(float4*)(wvv + 4) = *(const float4*)(Wr + (size_t)k * 2048 + d0 + 4);
    float s = 0.f;
#pragma unroll
    for (int j = 0; j < 8; ++j) s += hv[j] * wvv[j];
    acc[k] = s;
  }
#pragma unroll
  for (int off = 32; off > 0; off >>= 1)
#pragma unroll
    for (int k = 0; k < 8; ++k) acc[k] += __shfl_down(acc[k], off);
  __shared__ float red[4][8];
  __shared__ float logits[8];
  if (lane == 0)
#pragma unroll
    for (int k = 0; k < 8; ++k) red[wid][k] = acc[k];
  __syncthreads();
  if (tid < 8)
    logits[tid] = red[0][tid] + red[1][tid] + red[2][tid] + red[3][tid] + br[tid];
  __syncthreads();
  if (tid == 0) {
    float mx = logits[0];
#pragma unroll
    for (int k = 1; k < 8; ++k) mx = fmaxf(mx, logits[k]);
    float e[8], se = 0.f;
#pragma unroll
    for (int k = 0; k < 8; ++k) {
      e[k] = expf(logits[k] - mx);
      se += e[k];
    }
    const float is = 1.f / se;
#pragma unroll
    for (int k = 0; k < 8; ++k) w[(size_t)a * 8 + k] = e[k] * is;
  }
  if (mask[a] == 0) {
    const int i = ru[a];
    short8 o;
#pragma unroll
    for (int j = 0; j < 8; ++j) o[j] = (short)f2bf(hv[j]);
    *(short8*)(hbc + (size_t)i * 2048 + d0) = o;
  }
}

// ---------------- fused transpose-pack of W1 and W2 (one launch) ----------
// W1 [k][2048][512] -> B1t[(k*512+f)*2048 + d]
// W2 [k][512][2048] -> B2t[d*4096 + k*512 + f]
__global__ void tpack_kernel(const float* __restrict__ W1,
                             const float* __restrict__ W2,
                             unsigned short* __restrict__ B1t,
                             unsigned short* __restrict__ B2t) {
  __shared__ float tile[32][33];
  int id = blockIdx.x;
  const float* src;
  unsigned short* dst;
  int C, c0, r0;
  size_t dstStride;
  if (id < 8192) {  // W1: 8 experts x (16 cblk x 64 rblk)
    const int k = id >> 10, rem = id & 1023;
    const int cblk = rem >> 6, rblk = rem & 63;
    src = W1 + (size_t)k * 2048 * 512;
    dst = B1t + (size_t)k * 512 * 2048;
    C = 512; dstStride = 2048;
    c0 = cblk * 32; r0 = rblk * 32;
  } else {          // W2: 8 experts x (64 cblk x 16 rblk)
    id -= 8192;
    const int k = id >> 10, rem = id & 1023;
    const int cblk = rem >> 4, rblk = rem & 15;
    src = W2 + (size_t)k * 512 * 2048;
    dst = B2t + (size_t)k * 512;
    C = 2048; dstStride = 4096;
    c0 = cblk * 32; r0 = rblk * 32;
  }
  const int tx = threadIdx.x;  // 0..31
  const int ty = threadIdx.y;  // 0..7
#pragma unroll
  for (int i = 0; i < 4; ++i)
    tile[ty + 8 * i][tx] = src[(size_t)(r0 + ty + 8 * i) * C + (c0 + tx)];
  __syncthreads();
#pragma unroll
  for (int i = 0; i < 4; ++i) {
    const int c = c0 + ty + 8 * i;
    dst[(size_t)c * dstStride + (size_t)(r0 + tx)] = f2bf(tile[tx][ty + 8 * i]);
  }
}

// ---------------- GEMM C = A * Bt^T (A [M][Kd], Bt [N][Kd], both bf16 row-major) ----------------
// 128x128 tile, BK=32, 4 waves (2x2), 16x16x32 MFMA, global_load_lds w=16.
// 5-buffer depth-4 prefetch, counted vmcnt(12) steady state, one s_barrier
// per K-step. XCD swizzle: bn-major chunks per XCD (B-panels L2-resident).
// M limited at runtime by counts[cidx]; blocks past the limit exit.
template <int EPI>  // 0: store f32 C. 1: +bias, exact GELU, store bf16.
__global__ __launch_bounds__(256, 2) void gemm_bt_kernel(
    const unsigned short* __restrict__ A, const unsigned short* __restrict__ Bt,
    float* __restrict__ Cf, unsigned short* __restrict__ Cb,
    const float* __restrict__ bias, const int* __restrict__ counts, int cidx,
    int N, int Kd) {
  // XCD-aware bijective swizzle (nwg % 8 == 0 by construction).
  const int gx = gridDim.x, gy = gridDim.y;
  const int nwg = gx * gy;
  const int o = blockIdx.y * gx + blockIdx.x;
  const int q = nwg >> 3;
  const int swz = (o & 7) * q + (o >> 3);
  const int bn = (swz / gy) * 128;   // bn-major: per-XCD chunk spans few bns
  const int bm = (swz % gy) * 128;
  const int Mlim = counts[cidx];
  if (bm >= Mlim) return;
  // L[buf][0..4095] = A-tile (128 rows x 32 k), L[buf][4096..8191] = B-tile
  __shared__ __align__(16) unsigned short L[5][8192];
  const int tid = threadIdx.x;
  const int lane = tid & 63;
  const int wid = tid >> 6;
  const int wr = wid >> 1;
  const int wc = wid & 1;

  f32x4 acc[4][4];
#pragma unroll
  for (int m = 0; m < 4; ++m)
#pragma unroll
    for (int n = 0; n < 4; ++n) acc[m][n] = (f32x4){0.f, 0.f, 0.f, 0.f};

  const int srow = wid * 16 + (lane >> 2);
  const int scol = (lane & 3) * 8;
  const unsigned short* gA0 = A + (size_t)(bm + srow) * Kd + scol;
  const unsigned short* gA1 = gA0 + (size_t)64 * Kd;
  const unsigned short* gB0 = Bt + (size_t)(bn + srow) * Kd + scol;
  const unsigned short* gB1 = gB0 + (size_t)64 * Kd;

  const int aoff = (wr * 64 + (lane & 15)) * 32 + (lane >> 4) * 8;
  const int boff = (wc * 64 + (lane & 15)) * 32 + (lane >> 4) * 8;

#define STAGE(buf, t)                                                         \
  {                                                                           \
    const int k0_ = (t) << 5;                                                 \
    unsigned short* la_ = &L[(buf)][0] + wid * 512;                           \
    unsigned short* lb_ = &L[(buf)][4096] + wid * 512;                        \
    GLD16(gA0 + k0_, la_);                                                    \
    GLD16(gA1 + k0_, la_ + 2048);                                             \
    GLD16(gB0 + k0_, lb_);                                                    \
    GLD16(gB1 + k0_, lb_ + 2048);                                             \
  }

#define COMPUTE(buf)                                                          \
  {                                                                           \
    const unsigned short* As_ = &L[(buf)][0];                                 \
    const unsigned short* Bs_ = &L[(buf)][4096];                              \
    bf16x8 af[4], bfr[4];                                                     \
    _Pragma("unroll") for (int m = 0; m < 4; ++m) af[m] =                     \
        __builtin_bit_cast(bf16x8, *(const short8*)(As_ + aoff + m * 512));   \
    _Pragma("unroll") for (int n = 0; n < 4; ++n) bfr[n] =                    \
        __builtin_bit_cast(bf16x8, *(const short8*)(Bs_ + boff + n * 512));   \
    _Pragma("unroll") for (int m = 0; m < 4; ++m)                             \
        _Pragma("unroll") for (int n = 0; n < 4; ++n) acc[m][n] =             \
            __builtin_amdgcn_mfma_f32_16x16x32_bf16(af[m], bfr[n],            \
                                                    acc[m][n], 0, 0, 0);      \
  }

  const int nt = Kd >> 5;  // 64 or 128, always >= 5
  STAGE(0, 0);
  STAGE(1, 1);
  STAGE(2, 2);
  STAGE(3, 3);
  int cb = 0, sb = 4;
#pragma unroll 1
  for (int t = 0; t < nt - 4; ++t) {
    asm volatile("s_waitcnt vmcnt(12)" ::: "memory");  // tile t landed (mine)
    __builtin_amdgcn_s_barrier();                      // all landed t; t-1 reads done
    __builtin_amdgcn_sched_barrier(0);
    STAGE(sb, t + 4);  // overwrites tile t-1's buffer: safe post-barrier
    COMPUTE(cb);
    cb = (cb == 4) ? 0 : cb + 1;
    sb = (sb == 4) ? 0 : sb + 1;
  }
  {
    asm volatile("s_waitcnt vmcnt(12)" ::: "memory");
    __builtin_amdgcn_s_barrier();
    __builtin_amdgcn_sched_barrier(0);
    COMPUTE(cb);
    cb = (cb == 4) ? 0 : cb + 1;
  }
  {
    asm volatile("s_waitcnt vmcnt(8)" ::: "memory");
    __builtin_amdgcn_s_barrier();
    __builtin_amdgcn_sched_barrier(0);
    COMPUTE(cb);
    cb = (cb == 4) ? 0 : cb + 1;
  }
  {
    asm volatile("s_waitcnt vmcnt(4)" ::: "memory");
    __builtin_amdgcn_s_barrier();
    __builtin_amdgcn_sched_barrier(0);
    COMPUTE(cb);
    cb = (cb == 4) ? 0 : cb + 1;
  }
  {
    asm volatile("s_waitcnt vmcnt(0)" ::: "memory");
    __builtin_amdgcn_s_barrier();
    __builtin_amdgcn_sched_barrier(0);
    COMPUTE(cb);
  }
#undef STAGE
#undef COMPUTE

  // C/D layout: col = lane&15, row = (lane>>4)*4 + i (m89/m91-verified)
  const int r0 = bm + wr * 64 + (lane >> 4) * 4;
  const int c0 = bn + wc * 64 + (lane & 15);
#pragma unroll
  for (int m = 0; m < 4; ++m) {
#pragma unroll
    for (int n = 0; n < 4; ++n) {
      const int col = c0 + n * 16;
#pragma unroll
      for (int i = 0; i < 4; ++i) {
        const int row = r0 + m * 16 + i;
        if (row >= Mlim) continue;
        const size_t off = (size_t)row * N + col;
        float v = acc[m][n][i];
        if (EPI == 1) {
          v += bias[col];
          v = 0.5f * v * (1.0f + erff(v * 0.70710678118654752f));  // exact GELU
          Cb[off] = f2bf(v);
        } else {
          Cf[off] = v;
        }
      }
    }
  }
}

// ---------------- windowed neighbor sum + router weighting (compact) -------
__global__ void window_kernel(const unsigned short* __restrict__ Act_c,
                              const float* __restrict__ w,
                              const int* __restrict__ msk_idx,
                              const int* __restrict__ ru,
                              const int* __restrict__ rptr,
                              const int* __restrict__ counts,
                              unsigned short* __restrict__ G_c) {
  const int i = blockIdx.y;
  if (i >= counts[1]) return;
  const int a = msk_idx[i];
  const int s = a & 2047;
  const int tb = a & ~2047;
  const int r = rptr[0];
  const int lo = max(s - r, 0), hi = min(s + r, 2047);
  const int jlo = ru[tb + lo], jhi = ru[tb + hi + 1];
  const int c = blockIdx.x * 2048 + threadIdx.x * 8;
  float acc[8] = {0.f, 0.f, 0.f, 0.f, 0.f, 0.f, 0.f, 0.f};
  for (int j = jlo; j < jhi; ++j) {
    const short8 v = *(const short8*)(Act_c + (size_t)j * 4096 + c);
#pragma unroll
    for (int jj = 0; jj < 8; ++jj) acc[jj] += bf2f((unsigned short)v[jj]);
  }
  const float wv = w[(size_t)a * 8 + (c >> 9)];
  short8 o8;
#pragma unroll
  for (int jj = 0; jj < 8; ++jj) o8[jj] = (short)f2bf(acc[jj] * wv);
  *(short8*)(G_c + (size_t)i * 4096 + c) = o8;
}

// ---------------- final: bias-combine, mean, LN, blend ----------------
__global__ void final_kernel(const float* __restrict__ h,
                             const int* __restrict__ pos2row,
                             const float* __restrict__ w,
                             const float* __restrict__ b2,
                             const float* __restrict__ num_c,
                             const int* __restrict__ ru,
                             const int* __restrict__ rptr,
                             float* __restrict__ out) {
  const int a = blockIdx.x;
  const int tid = threadIdx.x;
  const int lane = tid & 63, wid = tid >> 6;
  const size_t base = (size_t)a * 2048;
  const int d0 = tid * 8;
  const int row = pos2row[a];
  if (row < 0) {  // block-uniform: exact fp32 pass-through
    const float4 x0 = *(const float4*)(h + base + d0);
    const float4 x1 = *(const float4*)(h + base + d0 + 4);
    *(float4*)(out + base + d0) = x0;
    *(float4*)(out + base + d0 + 4) = x1;
    return;
  }
  const int s = a & 2047;
  const int tb = a & ~2047;
  const int r = rptr[0];
  const int lo = max(s - r, 0), hi = min(s + r, 2047);
  const int cnt = ru[tb + hi + 1] - ru[tb + lo];
  float wk[8];
#pragma unroll
  for (int k = 0; k < 8; ++k) wk[k] = w[(size_t)a * 8 + k];
  const float cntf = (float)cnt;
  const float icnt = 1.0f / cntf;
  float mval[8];
  float s1 = 0.f, s2 = 0.f;
#pragma unroll
  for (int j = 0; j < 8; ++j) {
    const int d = d0 + j;
    float wb2 = 0.f;
#pragma unroll
    for (int k = 0; k < 8; ++k) wb2 += wk[k] * b2[(size_t)k * 2048 + d];
    const float v = (num_c[(size_t)row * 2048 + d] + cntf * wb2) * icnt;
    mval[j] = v;
    s1 += v;
    s2 += v * v;
  }
#pragma unroll
  for (int off = 32; off > 0; off >>= 1) {
    s1 += __shfl_down(s1, off);
    s2 += __shfl_down(s2, off);
  }
  __shared__ float red[8];
  if (lane == 0) {
    red[wid] = s1;
    red[4 + wid] = s2;
  }
  __syncthreads();
  const float S1 = red[0] + red[1] + red[2] + red[3];
  const float S2 = red[4] + red[5] + red[6] + red[7];
  const float mu = S1 * (1.0f / 2048.0f);
  const float var = S2 * (1.0f / 2048.0f) - mu * mu;
  const float rin = rsqrtf(var + EPS);
#pragma unroll
  for (int j = 0; j < 8; ++j) {
    const int d = d0 + j;
    out[base + d] = h[base + d] + ALPHA * ((mval[j] - mu) * rin);
  }
}

// ---------------- launch ----------------
extern "C" void kernel_launch(void* const* d_in, const int* in_sizes, int n_in,
                              void* d_out, int out_size, void* d_ws,
                              size_t ws_size, hipStream_t stream) {
  const float* h = (const float*)d_in[0];
  const int* mask = (const int*)d_in[1];
  const float* Wr = (const float*)d_in[2];
  const float* br = (const float*)d_in[3];
  const float* W1 = (const float*)d_in[4];
  const float* b1 = (const float*)d_in[5];
  const float* W2 = (const float*)d_in[6];
  const float* b2 = (const float*)d_in[7];
  const int* rptr = (const int*)d_in[8];
  float* out = (float*)d_out;

  char* ws = (char*)d_ws;
  // layout (bytes):
  //   hbc  [4096*2048] bf16 @ 0          (16 MiB)  compact unmasked h, bf16
  //   B1t  [4096*2048] bf16 @ 16777216   (16 MiB)  W1^T stacked: [kf][d]
  //   B2t  [2048*4096] bf16 @ 33554432   (16 MiB)  W2^T stacked: [d][kf]
  //   Act_c[4096*4096] bf16 @ 50331648   (32 MiB)  (aliased by num_c f32 later)
  //   G_c  [4096*4096] bf16 @ 83886080   (32 MiB)
  //   w    [4096*8]    f32  @ 117440512  (128 KiB)
  //   ints: ru[4097+], unm_idx[4096], msk_idx[4096], pos2row[4096], counts[2]
  unsigned short* hbc = (unsigned short*)(ws + 0);
  unsigned short* B1t = (unsigned short*)(ws + 16777216);
  unsigned short* B2t = (unsigned short*)(ws + 33554432);
  unsigned short* Act_c = (unsigned short*)(ws + 50331648);
  unsigned short* G_c = (unsigned short*)(ws + 83886080);
  float* num_c = (float*)(ws + 50331648);  // alias Act_c (dead after window)
  float* wbuf = (float*)(ws + 117440512);
  int* ru = (int*)(ws + 117571584);
  int* unm_idx = ru + 4100;
  int* msk_idx = unm_idx + 4096;
  int* pos2row = msk_idx + 4096;
  int* counts = pos2row + 4096;

  scan_kernel<<<1, 1024, 0, stream>>>(mask, rptr, ru, unm_idx, msk_idx,
                                      pos2row, counts);
  packrouter_kernel<<<4096, 256, 0, stream>>>(h, mask, ru, Wr, br, wbuf, hbc);
  tpack_kernel<<<16384, dim3(32, 8), 0, stream>>>(W1, W2, B1t, B2t);
  // GEMM1: Act_c = gelu(hbc * B1t^T + b1)   [Nu x 4096], Kd=2048
  gemm_bt_kernel<1><<<dim3(32, 32), 256, 0, stream>>>(
      hbc, B1t, nullptr, Act_c, b1, counts, 0, 4096, 2048);
  // G_c = w * windowed-sum(Act_c)   [Nm x 4096]
  window_kernel<<<dim3(2, 4096), 256, 0, stream>>>(Act_c, wbuf, msk_idx, ru,
                                                   rptr, counts, G_c);
  // GEMM2: num_c = G_c * B2t^T   [Nm x 2048], Kd=4096
  gemm_bt_kernel<0><<<dim3(16, 32), 256, 0, stream>>>(
      G_c, B2t, num_c, nullptr, nullptr, counts, 1, 2048, 4096);
  final_kernel<<<4096, 256, 0, stream>>>(h, pos2row, wbuf, b2, num_c, ru,
                                         rptr, out);
}

// Round 5
// 308.493 us; speedup vs baseline: 1.1247x; 1.1247x over previous
//
#include <hip/hip_runtime.h>
#include <hip/hip_bf16.h>
#include <math.h>

// ALALLaDA router blend, factored + row-compacted form:
//   prep: scan (ru/msk_idx/pos2row/counts) + router softmax + bf16 compact
//         pack of unmasked h rows + W1/W2 transpose-pack  (ONE kernel)
//   Act_c[i, kf] = gelu(h_unm[i,:]·W1 + b1)               (GEMM1, M=Nu)
//   G_c[i, kf]   = w[a]*sum_{j in win} Act_c[j]           (window kernel)
//   num_c[i,:]   = G_c[i,:]·W2s                           (GEMM2, M=Nm)
//   out = h + 0.08*LN((num_c+cnt*w·b2)/cnt) at active masked positions.
// GEMM: 128x128 tile, BK=64, 2-buffer, counted vmcnt(8), one stage per step
// after compute (T3/T4), T2 XOR-swizzle (16B slots, slot^=row&7) applied as
// linear-LDS-dest + inverse-permuted global source + swizzled ds_read
// (rule #21). LDS 64KB -> 2 blocks/CU.

#define ALPHA 0.08f
#define EPS 1e-5f

typedef __attribute__((ext_vector_type(8))) __bf16 bf16x8;
typedef __attribute__((ext_vector_type(8))) short short8;
typedef __attribute__((ext_vector_type(4))) float f32x4;

__device__ __forceinline__ unsigned short f2bf(float f) {
  unsigned u = __float_as_uint(f);
  u += 0x7fffu + ((u >> 16) & 1u);
  return (unsigned short)(u >> 16);
}
__device__ __forceinline__ float bf2f(unsigned short b) {
  return __uint_as_float(((unsigned)b) << 16);
}

#define GLD16(gptr, lptr)                                                     \
  __builtin_amdgcn_global_load_lds(                                           \
      (const __attribute__((address_space(1))) void*)(gptr),                  \
      (__attribute__((address_space(3))) void*)(lptr), 16, 0, 0)

__device__ __forceinline__ int wave_incl_scan(int v, int lane) {
#pragma unroll
  for (int off = 1; off < 64; off <<= 1) {
    int t = __shfl_up(v, off);
    if (lane >= off) v += t;
  }
  return v;
}

// ---------------- prep: tpack (blocks 0..16383) + packrouter (16384..20479)
//                  + scan (block 20480), 256 threads each ----------------
__global__ __launch_bounds__(256) void prep_kernel(
    const float* __restrict__ h, const int* __restrict__ mask,
    const float* __restrict__ Wr, const float* __restrict__ br,
    const float* __restrict__ W1, const float* __restrict__ W2,
    const int* __restrict__ rptr, float* __restrict__ w,
    unsigned short* __restrict__ hbc, unsigned short* __restrict__ B1t,
    unsigned short* __restrict__ B2t, int* __restrict__ ru,
    int* __restrict__ msk_idx, int* __restrict__ pos2row,
    int* __restrict__ counts) {
  const int bid = blockIdx.x;
  const int tid = threadIdx.x;
  const int lane = tid & 63, wv = tid >> 6;

  if (bid < 16384) {  // ---- transpose-pack W1 / W2 ----
    __shared__ float tile[32][33];
    int id = bid;
    const float* src;
    unsigned short* dst;
    int C, c0, r0;
    size_t dstStride;
    if (id < 8192) {  // W1 [k][2048][512] -> B1t[(k*512+f)*2048 + d]
      const int k = id >> 10, rem = id & 1023;
      src = W1 + (size_t)k * 2048 * 512;
      dst = B1t + (size_t)k * 512 * 2048;
      C = 512; dstStride = 2048;
      c0 = (rem >> 6) * 32; r0 = (rem & 63) * 32;
    } else {          // W2 [k][512][2048] -> B2t[d*4096 + k*512 + f]
      id -= 8192;
      const int k = id >> 10, rem = id & 1023;
      src = W2 + (size_t)k * 512 * 2048;
      dst = B2t + (size_t)k * 512;
      C = 2048; dstStride = 4096;
      c0 = (rem >> 4) * 32; r0 = (rem & 15) * 32;
    }
    const int tx = tid & 31, ty = tid >> 5;
#pragma unroll
    for (int i = 0; i < 4; ++i)
      tile[ty + 8 * i][tx] = src[(size_t)(r0 + ty + 8 * i) * C + (c0 + tx)];
    __syncthreads();
#pragma unroll
    for (int i = 0; i < 4; ++i) {
      const int c = c0 + ty + 8 * i;
      dst[(size_t)c * dstStride + (size_t)(r0 + tx)] =
          f2bf(tile[tx][ty + 8 * i]);
    }
    return;
  }

  if (bid < 20480) {  // ---- router softmax + compact bf16 pack of h ----
    const int a = bid - 16384;
    const size_t base = (size_t)a * 2048;
    const int d0 = tid * 8;
    float hv[8];
    *(float4*)(hv) = *(const float4*)(h + base + d0);
    *(float4*)(hv + 4) = *(const float4*)(h + base + d0 + 4);
    float acc[8];
#pragma unroll
    for (int k = 0; k < 8; ++k) {
      float wvv[8];
      *(float4*)(wvv) = *(const float4*)(Wr + (size_t)k * 2048 + d0);
      *(float4*)(wvv + 4) = *(const float4*)(Wr + (size_t)k * 2048 + d0 + 4);
      float s = 0.f;
#pragma unroll
      for (int j = 0; j < 8; ++j) s += hv[j] * wvv[j];
      acc[k] = s;
    }
    // my compact row index: zeros in mask[0..a)  (self-computed, no dep)
    int c0n = 0;
    {
      const int4* m4p = (const int4*)mask;
#pragma unroll
      for (int q = 0; q < 4; ++q) {
        const int4 v = m4p[tid * 4 + q];
        const int b0 = tid * 16 + q * 4;
        c0n += (v.x == 0 && b0 + 0 < a);
        c0n += (v.y == 0 && b0 + 1 < a);
        c0n += (v.z == 0 && b0 + 2 < a);
        c0n += (v.w == 0 && b0 + 3 < a);
      }
    }
#pragma unroll
    for (int off = 32; off > 0; off >>= 1) {
      c0n += __shfl_down(c0n, off);
#pragma unroll
      for (int k = 0; k < 8; ++k) acc[k] += __shfl_down(acc[k], off);
    }
    __shared__ float red[4][8];
    __shared__ float logits[8];
    __shared__ int rucnt[4];
    __shared__ int rubc;
    if (lane == 0) {
#pragma unroll
      for (int k = 0; k < 8; ++k) red[wv][k] = acc[k];
      rucnt[wv] = c0n;
    }
    __syncthreads();
    if (tid < 8)
      logits[tid] =
          red[0][tid] + red[1][tid] + red[2][tid] + red[3][tid] + br[tid];
    if (tid == 0) rubc = rucnt[0] + rucnt[1] + rucnt[2] + rucnt[3];
    __syncthreads();
    if (tid == 0) {
      float mx = logits[0];
#pragma unroll
      for (int k = 1; k < 8; ++k) mx = fmaxf(mx, logits[k]);
      float e[8], se = 0.f;
#pragma unroll
      for (int k = 0; k < 8; ++k) {
        e[k] = expf(logits[k] - mx);
        se += e[k];
      }
      const float is = 1.f / se;
#pragma unroll
      for (int k = 0; k < 8; ++k) w[(size_t)a * 8 + k] = e[k] * is;
    }
    if (mask[a] == 0) {
      const int i = rubc;
      short8 o;
#pragma unroll
      for (int j = 0; j < 8; ++j) o[j] = (short)f2bf(hv[j]);
      *(short8*)(hbc + (size_t)i * 2048 + d0) = o;
    }
    return;
  }

  // ---- scan block (bid == 20480): ru, msk_idx, pos2row, counts ----
  {
    __shared__ int sru[4097];
    __shared__ int wsum[4];
    __shared__ int wsum2[4];
    const int t0 = tid * 16;
    int mv[16];
    {
      const int4* p = (const int4*)mask;
#pragma unroll
      for (int q = 0; q < 4; ++q) {
        const int4 v = p[tid * 4 + q];
        mv[q * 4 + 0] = v.x; mv[q * 4 + 1] = v.y;
        mv[q * 4 + 2] = v.z; mv[q * 4 + 3] = v.w;
      }
    }
    int f[16];
    int c = 0;
#pragma unroll
    for (int e = 0; e < 16; ++e) { f[e] = (mv[e] == 0); c += f[e]; }
    const int isc = wave_incl_scan(c, lane);
    if (lane == 63) wsum[wv] = isc;
    __syncthreads();
    if (tid == 0) {
      int accs = 0;
#pragma unroll
      for (int i = 0; i < 4; ++i) { int v = wsum[i]; wsum[i] = accs; accs += v; }
      sru[4096] = accs;
      ru[4096] = accs;
      counts[0] = accs;
    }
    __syncthreads();
    int ex = wsum[wv] + isc - c;
#pragma unroll
    for (int e = 0; e < 16; ++e) {
      sru[t0 + e] = ex;
      ru[t0 + e] = ex;
      ex += f[e];
    }
    __syncthreads();
    const int r = rptr[0];
    int g[16];
    int c2 = 0;
#pragma unroll
    for (int e = 0; e < 16; ++e) {
      const int t = t0 + e;
      const int s = t & 2047, tb = t & ~2047;
      const int lo = max(s - r, 0), hi = min(s + r, 2047);
      const int cnt = sru[tb + hi + 1] - sru[tb + lo];
      g[e] = (mv[e] != 0 && cnt > 0) ? 1 : 0;
      c2 += g[e];
    }
    const int isc2 = wave_incl_scan(c2, lane);
    if (lane == 63) wsum2[wv] = isc2;
    __syncthreads();
    if (tid == 0) {
      int accs = 0;
#pragma unroll
      for (int i = 0; i < 4; ++i) { int v = wsum2[i]; wsum2[i] = accs; accs += v; }
      counts[1] = accs;
    }
    __syncthreads();
    int ex2 = wsum2[wv] + isc2 - c2;
#pragma unroll
    for (int e = 0; e < 16; ++e) {
      const int t = t0 + e;
      pos2row[t] = g[e] ? ex2 : -1;
      if (g[e]) msk_idx[ex2] = t;
      ex2 += g[e];
    }
  }
}

// ---------------- GEMM C = A * Bt^T (A [M][Kd], Bt [N][Kd], bf16 row-major)
// 128x128 tile, BK=64, 4 waves (2x2), 16x16x32 MFMA, global_load_lds w=16.
// 2 LDS buffers (64KB), counted vmcnt(8): stage t+2 after computing t.
// T2 swizzle: phys(row, slot16B) = logical(row, slot ^ (row&7)); staging
// pre-permutes the per-lane GLOBAL source column, ds_read XORs the slot.
// M limited at runtime by counts[cidx]; blocks past the limit exit.
template <int EPI>  // 0: store f32 C. 1: +bias, exact GELU, store bf16.
__global__ __launch_bounds__(256, 2) void gemm_bt_kernel(
    const unsigned short* __restrict__ A, const unsigned short* __restrict__ Bt,
    float* __restrict__ Cf, unsigned short* __restrict__ Cb,
    const float* __restrict__ bias, const int* __restrict__ counts, int cidx,
    int N, int Kd) {
  const int Mlim = counts[cidx];
  const int bm = blockIdx.y * 128;
  if (bm >= Mlim) return;
  // L[buf][0..8191] = A-tile (128 rows x 64 k), [8192..16383] = B-tile
  __shared__ __align__(16) unsigned short L[2][16384];
  const int tid = threadIdx.x;
  const int lane = tid & 63;
  const int wid = tid >> 6;
  const int bn = blockIdx.x * 128;
  const int wr = wid >> 1;
  const int wc = wid & 1;

  f32x4 acc[4][4];
#pragma unroll
  for (int m = 0; m < 4; ++m)
#pragma unroll
    for (int n = 0; n < 4; ++n) acc[m][n] = (f32x4){0.f, 0.f, 0.f, 0.f};

  // staging: wave w covers rows [w*32, w*32+32); inst j adds 8 rows.
  // lane l -> row_local l>>3, slot l&7; SOURCE column pre-permuted by the
  // inverse swizzle: scol = ((l&7) ^ (l>>3)) * 8 elems.
  const int l8 = lane >> 3;
  const int scol = ((lane & 7) ^ l8) * 8;
  const unsigned short* gA = A + (size_t)(bm + wid * 32 + l8) * Kd + scol;
  const unsigned short* gB = Bt + (size_t)(bn + wid * 32 + l8) * Kd + scol;

  // compute-side swizzled read offsets (shorts)
  const int arow = (wr * 64 + (lane & 15)) * 64;
  const int brow = (wc * 64 + (lane & 15)) * 64;
  const int t16 = lane >> 4;  // k-block 0..3 (16B slots 0..3 / 4..7 per kk)
  const int x7 = lane & 7;    // == row & 7 for this lane's fragment rows
  const int s0 = (t16 ^ x7) * 8;        // kk=0: slot t16
  const int s1 = ((4 + t16) ^ x7) * 8;  // kk=1: slot 4+t16

#define STAGE(buf, t)                                                         \
  {                                                                           \
    const int k0_ = (t) << 6;                                                 \
    unsigned short* la_ = &L[(buf)][0] + wid * 2048;                          \
    unsigned short* lb_ = &L[(buf)][8192] + wid * 2048;                       \
    GLD16(gA + k0_, la_);                                                     \
    GLD16(gA + (size_t)8 * Kd + k0_, la_ + 512);                              \
    GLD16(gA + (size_t)16 * Kd + k0_, la_ + 1024);                            \
    GLD16(gA + (size_t)24 * Kd + k0_, la_ + 1536);                            \
    GLD16(gB + k0_, lb_);                                                     \
    GLD16(gB + (size_t)8 * Kd + k0_, lb_ + 512);                              \
    GLD16(gB + (size_t)16 * Kd + k0_, lb_ + 1024);                            \
    GLD16(gB + (size_t)24 * Kd + k0_, lb_ + 1536);                            \
  }

#define COMPUTE(buf)                                                          \
  {                                                                           \
    const unsigned short* As_ = &L[(buf)][0];                                 \
    const unsigned short* Bs_ = &L[(buf)][8192];                              \
    bf16x8 a0[4], a1[4], b0[4], b1[4];                                        \
    _Pragma("unroll") for (int m = 0; m < 4; ++m) {                           \
      a0[m] = __builtin_bit_cast(bf16x8,                                      \
                                 *(const short8*)(As_ + arow + m * 1024 + s0)); \
      a1[m] = __builtin_bit_cast(bf16x8,                                      \
                                 *(const short8*)(As_ + arow + m * 1024 + s1)); \
    }                                                                         \
    _Pragma("unroll") for (int n = 0; n < 4; ++n) {                           \
      b0[n] = __builtin_bit_cast(bf16x8,                                      \
                                 *(const short8*)(Bs_ + brow + n * 1024 + s0)); \
      b1[n] = __builtin_bit_cast(bf16x8,                                      \
                                 *(const short8*)(Bs_ + brow + n * 1024 + s1)); \
    }                                                                         \
    _Pragma("unroll") for (int m = 0; m < 4; ++m)                             \
        _Pragma("unroll") for (int n = 0; n < 4; ++n) {                       \
      acc[m][n] = __builtin_amdgcn_mfma_f32_16x16x32_bf16(a0[m], b0[n],       \
                                                          acc[m][n], 0, 0, 0); \
      acc[m][n] = __builtin_amdgcn_mfma_f32_16x16x32_bf16(a1[m], b1[n],       \
                                                          acc[m][n], 0, 0, 0); \
    }                                                                         \
  }

  const int nt = Kd >> 6;  // 32 or 64
  STAGE(0, 0);
  STAGE(1, 1);
#pragma unroll 1
  for (int t = 0; t < nt - 2; ++t) {
    asm volatile("s_waitcnt vmcnt(8)" ::: "memory");  // my tile-t loads landed
    __builtin_amdgcn_s_barrier();                     // everyone's landed
    __builtin_amdgcn_sched_barrier(0);
    COMPUTE(t & 1);
    __builtin_amdgcn_s_barrier();  // all reads of buf t&1 done -> overwrite ok
    STAGE(t & 1, t + 2);
  }
  asm volatile("s_waitcnt vmcnt(8)" ::: "memory");
  __builtin_amdgcn_s_barrier();
  __builtin_amdgcn_sched_barrier(0);
  COMPUTE(nt & 1);
  asm volatile("s_waitcnt vmcnt(0)" ::: "memory");
  __builtin_amdgcn_s_barrier();
  __builtin_amdgcn_sched_barrier(0);
  COMPUTE((nt - 1) & 1);
#undef STAGE
#undef COMPUTE

  // C/D layout: col = lane&15, row = (lane>>4)*4 + i (m89/m91-verified)
  const int r0 = bm + wr * 64 + (lane >> 4) * 4;
  const int c0 = bn + wc * 64 + (lane & 15);
#pragma unroll
  for (int m = 0; m < 4; ++m) {
#pragma unroll
    for (int n = 0; n < 4; ++n) {
      const int col = c0 + n * 16;
#pragma unroll
      for (int i = 0; i < 4; ++i) {
        const int row = r0 + m * 16 + i;
        if (row >= Mlim) continue;
        const size_t off = (size_t)row * N + col;
        float v = acc[m][n][i];
        if (EPI == 1) {
          v += bias[col];
          v = 0.5f * v * (1.0f + erff(v * 0.70710678118654752f));  // exact GELU
          Cb[off] = f2bf(v);
        } else {
          Cf[off] = v;
        }
      }
    }
  }
}

// ---------------- windowed neighbor sum + router weighting (compact) -------
// XCD-chunked bijective token mapping: contiguous token chunks per XCD so
// overlapping windows hit the same XCD L2.
__global__ void window_kernel(const unsigned short* __restrict__ Act_c,
                              const float* __restrict__ w,
                              const int* __restrict__ msk_idx,
                              const int* __restrict__ ru,
                              const int* __restrict__ rptr,
                              const int* __restrict__ counts,
                              unsigned short* __restrict__ G_c) {
  const int Nm = counts[1];
  const int o = blockIdx.y;
  const int q = (Nm + 7) >> 3;
  const int y = o >> 3;
  if (y >= q) return;
  const int i = (o & 7) * q + y;
  if (i >= Nm) return;
  const int a = msk_idx[i];
  const int s = a & 2047;
  const int tb = a & ~2047;
  const int r = rptr[0];
  const int lo = max(s - r, 0), hi = min(s + r, 2047);
  const int jlo = ru[tb + lo], jhi = ru[tb + hi + 1];
  const int c = blockIdx.x * 2048 + threadIdx.x * 8;
  float acc[8] = {0.f, 0.f, 0.f, 0.f, 0.f, 0.f, 0.f, 0.f};
  for (int j = jlo; j < jhi; ++j) {
    const short8 v = *(const short8*)(Act_c + (size_t)j * 4096 + c);
#pragma unroll
    for (int jj = 0; jj < 8; ++jj) acc[jj] += bf2f((unsigned short)v[jj]);
  }
  const float wv = w[(size_t)a * 8 + (c >> 9)];
  short8 o8;
#pragma unroll
  for (int jj = 0; jj < 8; ++jj) o8[jj] = (short)f2bf(acc[jj] * wv);
  *(short8*)(G_c + (size_t)i * 4096 + c) = o8;
}

// ---------------- final: bias-combine, mean, LN, blend ----------------
__global__ void final_kernel(const float* __restrict__ h,
                             const int* __restrict__ pos2row,
                             const float* __restrict__ w,
                             const float* __restrict__ b2,
                             const float* __restrict__ num_c,
                             const int* __restrict__ ru,
                             const int* __restrict__ rptr,
                             float* __restrict__ out) {
  const int a = blockIdx.x;
  const int tid = threadIdx.x;
  const int lane = tid & 63, wid = tid >> 6;
  const size_t base = (size_t)a * 2048;
  const int d0 = tid * 8;
  const int row = pos2row[a];
  if (row < 0) {  // block-uniform: exact fp32 pass-through
    const float4 x0 = *(const float4*)(h + base + d0);
    const float4 x1 = *(const float4*)(h + base + d0 + 4);
    *(float4*)(out + base + d0) = x0;
    *(float4*)(out + base + d0 + 4) = x1;
    return;
  }
  const int s = a & 2047;
  const int tb = a & ~2047;
  const int r = rptr[0];
  const int lo = max(s - r, 0), hi = min(s + r, 2047);
  const int cnt = ru[tb + hi + 1] - ru[tb + lo];
  float wk[8];
#pragma unroll
  for (int k = 0; k < 8; ++k) wk[k] = w[(size_t)a * 8 + k];
  const float cntf = (float)cnt;
  const float icnt = 1.0f / cntf;
  float mval[8];
  float s1 = 0.f, s2 = 0.f;
#pragma unroll
  for (int j = 0; j < 8; ++j) {
    const int d = d0 + j;
    float wb2 = 0.f;
#pragma unroll
    for (int k = 0; k < 8; ++k) wb2 += wk[k] * b2[(size_t)k * 2048 + d];
    const float v = (num_c[(size_t)row * 2048 + d] + cntf * wb2) * icnt;
    mval[j] = v;
    s1 += v;
    s2 += v * v;
  }
#pragma unroll
  for (int off = 32; off > 0; off >>= 1) {
    s1 += __shfl_down(s1, off);
    s2 += __shfl_down(s2, off);
  }
  __shared__ float red[8];
  if (lane == 0) {
    red[wid] = s1;
    red[4 + wid] = s2;
  }
  __syncthreads();
  const float S1 = red[0] + red[1] + red[2] + red[3];
  const float S2 = red[4] + red[5] + red[6] + red[7];
  const float mu = S1 * (1.0f / 2048.0f);
  const float var = S2 * (1.0f / 2048.0f) - mu * mu;
  const float rin = rsqrtf(var + EPS);
#pragma unroll
  for (int j = 0; j < 8; ++j) {
    const int d = d0 + j;
    out[base + d] = h[base + d] + ALPHA * ((mval[j] - mu) * rin);
  }
}

// ---------------- launch ----------------
extern "C" void kernel_launch(void* const* d_in, const int* in_sizes, int n_in,
                              void* d_out, int out_size, void* d_ws,
                              size_t ws_size, hipStream_t stream) {
  const float* h = (const float*)d_in[0];
  const int* mask = (const int*)d_in[1];
  const float* Wr = (const float*)d_in[2];
  const float* br = (const float*)d_in[3];
  const float* W1 = (const float*)d_in[4];
  const float* b1 = (const float*)d_in[5];
  const float* W2 = (const float*)d_in[6];
  const float* b2 = (const float*)d_in[7];
  const int* rptr = (const int*)d_in[8];
  float* out = (float*)d_out;

  char* ws = (char*)d_ws;
  // layout (bytes):
  //   hbc  [4096*2048] bf16 @ 0          (16 MiB)  compact unmasked h, bf16
  //   B1t  [4096*2048] bf16 @ 16777216   (16 MiB)  W1^T stacked: [kf][d]
  //   B2t  [2048*4096] bf16 @ 33554432   (16 MiB)  W2^T stacked: [d][kf]
  //   Act_c[4096*4096] bf16 @ 50331648   (32 MiB)  (aliased by num_c f32)
  //   G_c  [4096*4096] bf16 @ 83886080   (32 MiB)
  //   w    [4096*8]    f32  @ 117440512  (128 KiB)
  //   ints: ru[4097+], msk_idx[4096], pos2row[4096], counts[2]
  unsigned short* hbc = (unsigned short*)(ws + 0);
  unsigned short* B1t = (unsigned short*)(ws + 16777216);
  unsigned short* B2t = (unsigned short*)(ws + 33554432);
  unsigned short* Act_c = (unsigned short*)(ws + 50331648);
  unsigned short* G_c = (unsigned short*)(ws + 83886080);
  float* num_c = (float*)(ws + 50331648);  // alias Act_c (dead after window)
  float* wbuf = (float*)(ws + 117440512);
  int* ru = (int*)(ws + 117571584);
  int* msk_idx = ru + 4100;
  int* pos2row = msk_idx + 4096;
  int* counts = pos2row + 4096;

  // prep: tpack (16384) + packrouter (4096) + scan (1)
  prep_kernel<<<20481, 256, 0, stream>>>(h, mask, Wr, br, W1, W2, rptr, wbuf,
                                         hbc, B1t, B2t, ru, msk_idx, pos2row,
                                         counts);
  // GEMM1: Act_c = gelu(hbc * B1t^T + b1)   [Nu x 4096], Kd=2048
  gemm_bt_kernel<1><<<dim3(32, 32), 256, 0, stream>>>(
      hbc, B1t, nullptr, Act_c, b1, counts, 0, 4096, 2048);
  // G_c = w * windowed-sum(Act_c)   [Nm x 4096]
  window_kernel<<<dim3(2, 4096), 256, 0, stream>>>(Act_c, wbuf, msk_idx, ru,
                                                   rptr, counts, G_c);
  // GEMM2: num_c = G_c * B2t^T   [Nm x 2048], Kd=4096
  gemm_bt_kernel<0><<<dim3(16, 32), 256, 0, stream>>>(
      G_c, B2t, num_c, nullptr, nullptr, counts, 1, 2048, 4096);
  final_kernel<<<4096, 256, 0, stream>>>(h, pos2row, wbuf, b2, num_c, ru,
                                         rptr, out);
}